// Round 9
// baseline (360.735 us; speedup 1.0000x reference)
//
#include <hip/hip_runtime.h>
#include <hip/hip_bf16.h>
#include <hip/hip_cooperative_groups.h>

namespace cg = cooperative_groups;

typedef short bf16x8 __attribute__((ext_vector_type(8)));
typedef float f32x4 __attribute__((ext_vector_type(4)));

#define SS 2048
#define DD 1024
#define RR 128

__device__ __forceinline__ short f2bf(float x){
  unsigned u = __float_as_uint(x);
  u += 0x7fffu + ((u >> 16) & 1u);
  return (short)(u >> 16);
}
__device__ __forceinline__ float bf2f(short h){
  return __uint_as_float(((unsigned)(unsigned short)h) << 16);
}
__device__ __forceinline__ void gload16(const void* g, void* l){
  __builtin_amdgcn_global_load_lds((const __attribute__((address_space(1))) unsigned*)g,
                                   (__attribute__((address_space(3))) unsigned*)l, 16, 0, 0);
}
// swizzled short-index into a [rows][64] bf16 tile (phase B)
__device__ __forceinline__ int swz(int row, int c16){
  return row * 64 + ((c16 ^ (row & 7)) << 3);
}

// Cooperative fused kernel: 256 blocks x 512 threads, 1 block/CU (co-resident by contract).
// Phase A (blocks 0..31): proj -> pt transpose + hi/lo bf16 split.       grid.sync()
// Phase B (all): 64-row chunk of t = batch @ proj, double-buffered K.    grid.sync()
// Phase C (all): persistent symmetric-distance tiles, hi-only MFMA (err ~0.1 << 2.0 tol).
__global__ __launch_bounds__(512, 1) void fused_psd(
    const float* __restrict__ batch, const float* __restrict__ proj,
    short* __restrict__ pt_hi, short* __restrict__ pt_lo,
    short* __restrict__ t_hi, float* __restrict__ sqv,
    float* __restrict__ out){
  // smem map, phase B: Abuf0 0(hi8K,lo8K) | Abuf1 16K | Pbuf0 32K(hi16K,lo16K) | Pbuf1 64K | sqpart 96K
  // phase A: ftile [64][65] f32 at 0. phase C: A panel 0(32K) | B panel 32K; ftile f32 alias at 0.
  __shared__ __align__(16) char smem[98560];
  cg::grid_group grid = cg::this_grid();
  const int b = blockIdx.x;
  const int tid = threadIdx.x;
  const int w = tid >> 6, lane = tid & 63;
  const int lr = lane & 15, lg = lane >> 4;

  // ================= Phase A =================
  if (b < 32){
    float* ftile = (float*)smem;
    const int d0 = (b & 15) * 64, r0 = (b >> 4) * 64;
    #pragma unroll
    for (int i = 0; i < 8; ++i){
      int u = i * 512 + tid;
      int d = u >> 6, r = u & 63;
      ftile[d * 65 + r] = proj[(d0 + d) * RR + r0 + r];
    }
    __syncthreads();
    #pragma unroll
    for (int i = 0; i < 8; ++i){
      int u = i * 512 + tid;
      int r = u >> 6, d = u & 63;
      float x = ftile[d * 65 + r];
      short h = f2bf(x);
      short l = f2bf(x - bf2f(h));
      pt_hi[(r0 + r) * DD + d0 + d] = h;
      pt_lo[(r0 + r) * DD + d0 + d] = l;
    }
  }
  __threadfence();
  grid.sync();

  // ================= Phase B =================
  {
    const int wr = w & 3, wc = w >> 2;
    const int row0 = b * 64;
    const int colg = (lane & 7) ^ (lane >> 3);
    float* sqpart = (float*)(smem + 98304);
    if (tid < 64) sqpart[tid] = 0.f;
    f32x4 acc[4] = {{0.f,0.f,0.f,0.f}};
    const int arow = tid >> 3;                  // A-stage row for this thread
    const int akc = (tid & 7) * 8;              // A-stage col base (8 floats)
    const int asidx = arow * 64 + (((akc >> 3) ^ (arow & 7)) << 3);

    // prologue: stage tile 0 into buf0
    {
      float4 v0 = *(const float4*)(batch + (size_t)(row0 + arow) * DD + akc);
      float4 v1 = *(const float4*)(batch + (size_t)(row0 + arow) * DD + akc + 4);
      short hv[8], lv[8];
      float xs[8] = {v0.x,v0.y,v0.z,v0.w,v1.x,v1.y,v1.z,v1.w};
      #pragma unroll
      for (int e = 0; e < 8; ++e){ hv[e] = f2bf(xs[e]); lv[e] = f2bf(xs[e] - bf2f(hv[e])); }
      *(short4*)((short*)smem + asidx)            = make_short4(hv[0],hv[1],hv[2],hv[3]);
      *(short4*)((short*)smem + asidx + 4)        = make_short4(hv[4],hv[5],hv[6],hv[7]);
      *(short4*)((short*)(smem+8192) + asidx)     = make_short4(lv[0],lv[1],lv[2],lv[3]);
      *(short4*)((short*)(smem+8192) + asidx + 4) = make_short4(lv[4],lv[5],lv[6],lv[7]);
      #pragma unroll
      for (int q = 0; q < 2; ++q){
        int prow = w * 16 + q * 8 + (lane >> 3);
        gload16(pt_hi + prow * DD + colg * 8, (short*)(smem + 32768) + w * 1024 + q * 512);
        gload16(pt_lo + prow * DD + colg * 8, (short*)(smem + 49152) + w * 1024 + q * 512);
      }
      __syncthreads();
    }
    #pragma unroll 1
    for (int t = 0; t < 16; ++t){
      const int cur = t & 1;
      char* curA = smem + cur * 16384;
      char* curP = smem + 32768 + cur * 32768;
      char* nxtA = smem + (cur ^ 1) * 16384;
      char* nxtP = smem + 32768 + (cur ^ 1) * 32768;
      const bool pre = (t < 15);
      float4 pv0, pv1;
      if (pre){
        const int kn = (t + 1) * 64;
        pv0 = *(const float4*)(batch + (size_t)(row0 + arow) * DD + kn + akc);
        pv1 = *(const float4*)(batch + (size_t)(row0 + arow) * DD + kn + akc + 4);
        #pragma unroll
        for (int q = 0; q < 2; ++q){
          int prow = w * 16 + q * 8 + (lane >> 3);
          gload16(pt_hi + prow * DD + kn + colg * 8, (short*)nxtP + w * 1024 + q * 512);
          gload16(pt_lo + prow * DD + kn + colg * 8, (short*)(nxtP + 16384) + w * 1024 + q * 512);
        }
      }
      #pragma unroll
      for (int ks = 0; ks < 2; ++ks){
        int c16 = ks * 4 + lg;
        bf16x8 ah = *(const bf16x8*)((short*)curA + swz(wr * 16 + lr, c16));
        bf16x8 al = *(const bf16x8*)((short*)(curA + 8192) + swz(wr * 16 + lr, c16));
        bf16x8 bh[4], bl[4];
        #pragma unroll
        for (int n = 0; n < 4; ++n){
          int prow = wc * 64 + n * 16 + lr;
          bh[n] = *(const bf16x8*)((short*)curP + swz(prow, c16));
          bl[n] = *(const bf16x8*)((short*)(curP + 16384) + swz(prow, c16));
        }
        #pragma unroll
        for (int n = 0; n < 4; ++n)
          acc[n] = __builtin_amdgcn_mfma_f32_16x16x32_bf16(ah, bh[n], acc[n], 0, 0, 0);
        #pragma unroll
        for (int n = 0; n < 4; ++n)
          acc[n] = __builtin_amdgcn_mfma_f32_16x16x32_bf16(ah, bl[n], acc[n], 0, 0, 0);
        #pragma unroll
        for (int n = 0; n < 4; ++n)
          acc[n] = __builtin_amdgcn_mfma_f32_16x16x32_bf16(al, bh[n], acc[n], 0, 0, 0);
      }
      if (pre){
        short hv[8], lv[8];
        float xs[8] = {pv0.x,pv0.y,pv0.z,pv0.w,pv1.x,pv1.y,pv1.z,pv1.w};
        #pragma unroll
        for (int e = 0; e < 8; ++e){ hv[e] = f2bf(xs[e]); lv[e] = f2bf(xs[e] - bf2f(hv[e])); }
        *(short4*)((short*)nxtA + asidx)            = make_short4(hv[0],hv[1],hv[2],hv[3]);
        *(short4*)((short*)nxtA + asidx + 4)        = make_short4(hv[4],hv[5],hv[6],hv[7]);
        *(short4*)((short*)(nxtA+8192) + asidx)     = make_short4(lv[0],lv[1],lv[2],lv[3]);
        *(short4*)((short*)(nxtA+8192) + asidx + 4) = make_short4(lv[4],lv[5],lv[6],lv[7]);
      }
      __syncthreads();
    }
    // epilogue: norms + bf16 round -> LDS bounce -> coalesced t_hi stores
    short* Th = (short*)(smem + 32768);
    #pragma unroll
    for (int r = 0; r < 4; ++r){
      int lrow = wr * 16 + lg * 4 + r;
      float s = 0.f;
      #pragma unroll
      for (int n = 0; n < 4; ++n){
        float x = acc[n][r];
        s += x * x;
        Th[lrow * 128 + wc * 64 + n * 16 + lr] = f2bf(x);
      }
      s += __shfl_xor(s, 1);
      s += __shfl_xor(s, 2);
      s += __shfl_xor(s, 4);
      s += __shfl_xor(s, 8);
      if (lr == 0) atomicAdd(&sqpart[lrow], s);
    }
    __syncthreads();
    #pragma unroll
    for (int ps = 0; ps < 2; ++ps){
      int u = ps * 512 + tid;
      int row = u >> 4, c8 = (u & 15) * 8;
      *(int4*)&t_hi[(size_t)(row0 + row) * RR + c8] = *(int4*)&Th[row * 128 + c8];
    }
    if (tid < 64) sqv[row0 + tid] = sqpart[tid];
  }
  __threadfence();
  grid.sync();

  // ================= Phase C =================
  {
    const int bi = b & 7;                      // batch == XCD (0.5 MB hi panel in local L2)
    const int lidx = b >> 3;
    const size_t tbase = (size_t)bi * SS * RR;
    float* outb = out + (size_t)bi * SS * SS;
    const float* sqb = sqv + bi * SS;
    const int srow = ((w & 1) << 2) | (lane >> 4);
    const int colg2 = (lane & 15) ^ srow;
    short* ldsA = (short*)smem;                // [128][128] bf16 swizzled
    short* ldsB = (short*)(smem + 32768);
    float* ftile = (float*)smem;               // 128x128 f32 alias
    #pragma unroll 1
    for (int pp = lidx; pp < 136; pp += 32){
      int p = pp, ti = 0;
      while (p >= 16 - ti){ p -= 16 - ti; ++ti; }
      const int tj = ti + p;
      const int i0 = ti * 128, j0 = tj * 128;
      const bool dg = (ti == tj);
      __syncthreads();                         // prior iter's ftile reads done
      #pragma unroll
      for (int q = 0; q < 4; ++q){
        int rl = q * 32 + w * 4;
        int gr = rl + (lane >> 4);
        gload16(t_hi + tbase + (size_t)(i0 + gr) * RR + colg2 * 8, &ldsA[rl * 128]);
        if (!dg)
          gload16(t_hi + tbase + (size_t)(j0 + gr) * RR + colg2 * 8, &ldsB[rl * 128]);
      }
      __syncthreads();
      short* ldsBB = dg ? ldsA : ldsB;
      f32x4 acc[8] = {{0.f,0.f,0.f,0.f}};
      const int ar = w * 16 + lr;
      const int aoff = ar * 128, asw = ar & 7;
      #pragma unroll
      for (int ks = 0; ks < 4; ++ks){
        int c16 = ks * 4 + lg;
        bf16x8 ah = *(const bf16x8*)&ldsA[aoff + ((c16 ^ asw) << 3)];
        bf16x8 bh[8];
        #pragma unroll
        for (int n = 0; n < 8; ++n){
          int br = n * 16 + lr;
          bh[n] = *(const bf16x8*)&ldsBB[br * 128 + ((c16 ^ (br & 7)) << 3)];
        }
        #pragma unroll
        for (int n = 0; n < 8; ++n)
          acc[n] = __builtin_amdgcn_mfma_f32_16x16x32_bf16(ah, bh[n], acc[n], 0, 0, 0);
      }
      __syncthreads();                         // frag reads done; panels dead
      if (!dg){                                // mirror tile straight from regs
        int rbase = w * 16 + lg * 4;
        float4 si4 = *(const float4*)&sqb[i0 + rbase];
        #pragma unroll
        for (int n = 0; n < 8; ++n){
          int col = n * 16 + lr;
          float sj = sqb[j0 + col];
          float4 mv;
          mv.x = si4.x + sj - 2.0f * acc[n][0];
          mv.y = si4.y + sj - 2.0f * acc[n][1];
          mv.z = si4.z + sj - 2.0f * acc[n][2];
          mv.w = si4.w + sj - 2.0f * acc[n][3];
          *(float4*)&outb[(size_t)(j0 + col) * SS + (i0 + rbase)] = mv;
        }
      }
      #pragma unroll
      for (int n = 0; n < 8; ++n)
        #pragma unroll
        for (int r = 0; r < 4; ++r)
          ftile[(w * 16 + lg * 4 + r) * 128 + n * 16 + lr] = acc[n][r];
      __syncthreads();
      #pragma unroll
      for (int v = 0; v < 8; ++v){
        int u = v * 512 + tid;
        int row = u >> 5, c4 = (u & 31) * 4;
        float4 d = *(float4*)&ftile[row * 128 + c4];
        float si = sqb[i0 + row];
        float4 sj = *(const float4*)&sqb[j0 + c4];
        float4 o;
        o.x = si + sj.x - 2.0f * d.x;
        o.y = si + sj.y - 2.0f * d.y;
        o.z = si + sj.z - 2.0f * d.z;
        o.w = si + sj.w - 2.0f * d.w;
        *(float4*)&outb[(size_t)(i0 + row) * SS + j0 + c4] = o;
      }
    }
  }
}

extern "C" void kernel_launch(void* const* d_in, const int* in_sizes, int n_in,
                              void* d_out, int out_size, void* d_ws, size_t ws_size,
                              hipStream_t stream) {
  const float* batch = (const float*)d_in[0];   // (8, 2048, 1024) f32
  const float* proj  = (const float*)d_in[1];   // (1024, 128) f32
  float* out = (float*)d_out;                   // (8, 2048, 2048) f32
  char* ws = (char*)d_ws;

  short* pt_hi = (short*)(ws);                  // 128x1024 bf16 = 256 KB
  short* pt_lo = (short*)(ws + 262144);         // 256 KB
  short* t_hi  = (short*)(ws + 524288);         // 16384x128 bf16 = 4 MB
  float* sqv   = (float*)(ws + 4718592);        // 16384 f32 = 64 KB

  void* args[7];
  args[0] = (void*)&batch;
  args[1] = (void*)&proj;
  args[2] = (void*)&pt_hi;
  args[3] = (void*)&pt_lo;
  args[4] = (void*)&t_hi;
  args[5] = (void*)&sqv;
  args[6] = (void*)&out;
  hipLaunchCooperativeKernel(fused_psd, dim3(256), dim3(512), args, 0, stream);
}